// Round 2
// baseline (1048.313 us; speedup 1.0000x reference)
//
#include <hip/hip_runtime.h>
#include <stdint.h>

typedef unsigned short u16;
typedef __attribute__((ext_vector_type(8))) short s8bf;   // 8 bf16 in 4 VGPRs
typedef __attribute__((ext_vector_type(4))) float f32x4;

#define N_TOK 8192
#define DIM   1024
#define HID   4096
#define NE    8
#define MAX_SLOTS 17408   // 16384 + 8*128 worst-case padding
#define MAX_TILES 160
#define TSTR  264         // transpose LDS row stride (u16): 528B, 16B-aligned

// ---- workspace layout (bytes) ----
#define OFF_W1T  ((size_t)0)                    // [E][HID][DIM] bf16  (n-major, k-contig)
#define OFF_Y    ((size_t)0)                    // y bf16 [MAX_SLOTS][DIM] — overlays dead W1T
#define OFF_W2T  ((size_t)67108864)             // [E][DIM][HID] bf16
#define OFF_XB   ((size_t)134217728)             // [N_TOK][DIM] bf16
#define OFF_H    ((size_t)150994944)            // [MAX_SLOTS][HID] bf16
#define OFF_TOS  ((size_t)293601280)            // token_of_slot int[MAX_SLOTS]
#define OFF_SOT  ((size_t)293670912)            // slot_of_token int[N_TOK*2]
#define OFF_TKI  ((size_t)293740544)            // topk idx int[N_TOK*2]
#define OFF_TKW  ((size_t)293806080)            // topk w  float[N_TOK*2]
#define OFF_CNT  ((size_t)293871616)            // counts int[8]
#define OFF_POF  ((size_t)293871680)            // padded offsets int[8]
#define OFF_CUR  ((size_t)293871744)            // cursors int[8]
#define OFF_NT   ((size_t)293871808)            // n_tiles int[1]
#define OFF_TE   ((size_t)293871872)            // tile_expert int[MAX_TILES]
#define OFF_TS   ((size_t)293872896)            // tile_slot0  int[MAX_TILES]

__device__ __forceinline__ u16 f2b(float v) {   // fp32 -> bf16 RNE
  union { float f; uint32_t u; } c; c.f = v;
  uint32_t u = c.u;
  return (u16)((u + 0x7FFFu + ((u >> 16) & 1u)) >> 16);
}
__device__ __forceinline__ float b2f(u16 b) {
  union { uint32_t u; float f; } c; c.u = ((uint32_t)b) << 16; return c.f;
}

// async global->LDS DMA, 16 B per lane. lds ptr wave-uniform; lane i -> l + i*16.
typedef const __attribute__((address_space(1))) uint32_t* gp32;
typedef __attribute__((address_space(3))) uint32_t* lp32;
__device__ __forceinline__ void gl_lds16(const u16* g, u16* l) {
  __builtin_amdgcn_global_load_lds((gp32)(const void*)g, (lp32)(void*)l, 16, 0, 0);
}

// ---- fused fp32 [R][C] -> bf16 [C][R] transpose, 256(R) x 64(C) tiles ----
__global__ __launch_bounds__(256) void transpose_to_bf16(
    const float* __restrict__ in, u16* __restrict__ out, int R, int C) {
  __shared__ u16 L[64 * TSTR];   // 33792 B
  int tiles_c = C >> 6, tiles_r = R >> 8;
  int per = tiles_c * tiles_r;
  int e = blockIdx.x / per, t = blockIdx.x % per;
  int tr = t / tiles_c, tc = t % tiles_c;
  const float* ip = in + (size_t)e * R * C + (size_t)(tr * 256) * C + tc * 64;
  u16* op = out + (size_t)e * R * C + (size_t)(tc * 64) * R + tr * 256;
  const int tid = threadIdx.x;
  const int c = tid & 63;
  const int rb0 = (tid >> 6) * 8;
  #pragma unroll
  for (int p = 0; p < 8; p++) {
    int rb = p * 32 + rb0;
    u16 tmp[8];
    #pragma unroll
    for (int j = 0; j < 8; j++) tmp[j] = f2b(ip[(size_t)(rb + j) * C + c]);
    *(uint4*)&L[c * TSTR + rb] = *(const uint4*)tmp;
  }
  __syncthreads();
  const int s = tid & 31, ocb = tid >> 5;
  #pragma unroll
  for (int p = 0; p < 8; p++) {
    int oc = p * 8 + ocb;
    uint4 v = *(const uint4*)&L[oc * TSTR + s * 8];
    *(uint4*)&op[(size_t)oc * R + s * 8] = v;
  }
}

// ---- x fp32 -> bf16 ----
__global__ __launch_bounds__(256) void convert_x(const float* __restrict__ x,
                                                 u16* __restrict__ xb) {
  size_t i = ((size_t)blockIdx.x * 256 + threadIdx.x) * 8;
  float4 v0 = *(const float4*)(x + i);
  float4 v1 = *(const float4*)(x + i + 4);
  u16 o[8] = {f2b(v0.x), f2b(v0.y), f2b(v0.z), f2b(v0.w),
              f2b(v1.x), f2b(v1.y), f2b(v1.z), f2b(v1.w)};
  *(uint4*)(xb + i) = *(const uint4*)o;
}

// ---- router: logits -> top2 -> renormalized weights (fp32). one wave/token ----
__global__ __launch_bounds__(256) void router_kernel(
    const float* __restrict__ x, const float* __restrict__ Wr,
    const float* __restrict__ br, int* __restrict__ tki, float* __restrict__ tkw,
    int* __restrict__ counts) {
  int wave = threadIdx.x >> 6, lane = threadIdx.x & 63;
  int t = blockIdx.x * 4 + wave;
  const float* xr = x + (size_t)t * DIM;
  float acc[8] = {0.f, 0.f, 0.f, 0.f, 0.f, 0.f, 0.f, 0.f};
  #pragma unroll
  for (int i = 0; i < 16; i++) {
    int d = lane + i * 64;
    float xv = xr[d];
    float4 wa = *(const float4*)(Wr + d * 8);
    float4 wb = *(const float4*)(Wr + d * 8 + 4);
    acc[0] += xv * wa.x; acc[1] += xv * wa.y; acc[2] += xv * wa.z; acc[3] += xv * wa.w;
    acc[4] += xv * wb.x; acc[5] += xv * wb.y; acc[6] += xv * wb.z; acc[7] += xv * wb.w;
  }
  #pragma unroll
  for (int e = 0; e < 8; e++)
    #pragma unroll
    for (int off = 32; off >= 1; off >>= 1)
      acc[e] += __shfl_xor(acc[e], off, 64);
  if (lane == 0) {
    float l[8];
    #pragma unroll
    for (int e = 0; e < 8; e++) l[e] = acc[e] + br[e];
    float l0 = -1e30f; int i0 = 0;
    #pragma unroll
    for (int e = 0; e < 8; e++) if (l[e] > l0) { l0 = l[e]; i0 = e; }
    float l1 = -1e30f; int i1 = 0;
    #pragma unroll
    for (int e = 0; e < 8; e++) if (e != i0 && l[e] > l1) { l1 = l[e]; i1 = e; }
    float w0 = 1.f / (1.f + expf(l1 - l0));
    tki[t * 2] = i0; tki[t * 2 + 1] = i1;
    tkw[t * 2] = w0; tkw[t * 2 + 1] = 1.f - w0;
    atomicAdd(&counts[i0], 1);
    atomicAdd(&counts[i1], 1);
  }
}

// ---- plan: padded per-expert offsets + tile list (parallel over experts) ----
__global__ void plan_kernel(const int* __restrict__ counts, int* __restrict__ poff,
                            int* __restrict__ cursor, int* __restrict__ ntiles,
                            int* __restrict__ tile_e, int* __restrict__ tile_s0) {
  int e = threadIdx.x;
  if (e < NE) {
    int po = 0, tb = 0;
    for (int i = 0; i < e; i++) {
      int tl = (counts[i] + 127) >> 7;
      po += tl << 7; tb += tl;
    }
    poff[e] = po;
    cursor[e] = 0;
    int tl = (counts[e] + 127) >> 7;
    for (int j = 0; j < tl; j++) { tile_e[tb + j] = e; tile_s0[tb + j] = po + j * 128; }
    if (e == NE - 1) ntiles[0] = tb + tl;
  }
}

// ---- scatter tokens into per-expert slots ----
__global__ __launch_bounds__(256) void scatter_kernel(
    const int* __restrict__ tki, const int* __restrict__ poff,
    int* __restrict__ cursor, int* __restrict__ token_of_slot,
    int* __restrict__ slot_of_token) {
  int t = blockIdx.x * 256 + threadIdx.x;
  #pragma unroll
  for (int k = 0; k < 2; k++) {
    int e = tki[t * 2 + k];
    int r = atomicAdd(&cursor[e], 1);
    int s = poff[e] + r;
    token_of_slot[s] = t;
    slot_of_token[t * 2 + k] = s;
  }
}

// ---- grouped GEMM: C[128x256]/block, 8 waves (2Mx4N), 16x16x32 bf16 MFMA ----
// Template-style schedule per 64-K tile (template ratio: >=16 MFMA per barrier
// pair; reads split 12/4 so the big read phase overlaps a full MFMA cluster):
//   P0: 12 ds_read_b128 (A m0-3 ks01 + B n01 ks01) -> bar -> 16 MFMA -> bar
//   P1:  4 ds_read_b128 (B n23 ks01)               -> bar -> 16 MFMA
//       -> lgkmcnt(0) -> bar   (all reads of buf[t&1] complete, block-wide)
//   ST:  6 global_load_lds for tile t+2 into buf[t&1] (safe: reads drained);
//       vmcnt(6) waits tile t+1's 6 loads (issued one tile ago) -> bar
// Depth-2 prefetch, counted vmcnt (never 0 except tail). sched_barrier(0)
// pins keep reads/stages inside their phase (raw s_barrier is not a fence).
// T2 swizzle: LDS row = 8 x 16B slots, slot index XOR (row&7); gl_lds dest
// linear, global SOURCE column inverse-permuted, ds_read applies same XOR.
// MODE 1: A rows gathered via token_of_slot, relu(acc+b1) -> h
// MODE 2: A rows = slots (h),               (acc+b2)      -> y
template <int MODE>
__global__ __launch_bounds__(512, 2) void moe_gemm(
    const u16* __restrict__ A, const u16* __restrict__ Bt,
    const float* __restrict__ bias, u16* __restrict__ Hout,
    const int* __restrict__ tile_e, const int* __restrict__ tile_s0,
    const int* __restrict__ ntiles, const int* __restrict__ token_of_slot,
    int K, int N, int NB) {
  __shared__ u16 SM[49152];   // 96 KB: A0@0, A1@8192, B0@16384, B1@32768 (u16 units)

  const int nblk = blockIdx.x % NB;     // n fastest -> XCD-stationary B stripes
  const int tileid = blockIdx.x / NB;
  if (tileid >= ntiles[0]) return;
  const int e = tile_e[tileid];
  const int slot0 = tile_s0[tileid];
  const int n0 = nblk * 256;
  const int T = K >> 6;                 // 64-K tiles

  const int tid = threadIdx.x;
  const int lane = tid & 63;
  const int wave = tid >> 6;
  const int wm = wave >> 2;             // 0..1 : 64-row M half
  const int wn = wave & 3;              // 0..3 : 64-col N quarter

  // ---- staging source pointers (inverse-swizzled global columns) ----
  // chunk c = l*512 + tid -> LDS row c>>3 = l*64 + (tid>>3), slot c&7 = tid&7
  const int srow = tid >> 3;
  const int sslot = tid & 7;
  const u16* aB[2];
  #pragma unroll
  for (int l = 0; l < 2; l++) {
    int row = l * 64 + srow;
    int scol = (sslot ^ (row & 7)) * 8;
    int arow;
    if (MODE == 1) { int t0 = token_of_slot[slot0 + row]; arow = t0 < 0 ? 0 : t0; }
    else arow = slot0 + row;
    aB[l] = A + (size_t)arow * K + scol;
  }
  const u16* bE = Bt + (size_t)e * N * K;
  const u16* bB[4];
  #pragma unroll
  for (int l = 0; l < 4; l++) {
    int row = l * 64 + srow;
    int scol = (sslot ^ (row & 7)) * 8;
    bB[l] = bE + (size_t)(n0 + row) * K + scol;
  }

  // bias preload BEFORE stages + vmcnt(0) pin, so in-loop vmcnt counts are exact
  const int colq = lane & 15;
  float bv[4];
  #pragma unroll
  for (int n = 0; n < 4; n++) bv[n] = bias[(size_t)e * N + n0 + wn * 64 + n * 16 + colq];
  asm volatile("s_waitcnt vmcnt(0)" ::: "memory");

  const int wb = wave * 64;             // lane0 chunk base within one load group
  // ---- prologue: stage K-tiles 0 and 1 (6 loads each, in order) ----
  #pragma unroll
  for (int tt = 0; tt < 2; tt++) {
    const int kq = tt * 64;
    u16* LA = SM + tt * 8192;
    u16* LB = SM + 16384 + tt * 16384;
    gl_lds16(aB[0] + kq, LA + wb * 8);
    gl_lds16(aB[1] + kq, LA + (512 + wb) * 8);
    gl_lds16(bB[0] + kq, LB + wb * 8);
    gl_lds16(bB[1] + kq, LB + (512 + wb) * 8);
    gl_lds16(bB[2] + kq, LB + (1024 + wb) * 8);
    gl_lds16(bB[3] + kq, LB + (1536 + wb) * 8);
  }
  asm volatile("s_waitcnt vmcnt(6)" ::: "memory");   // tile0 landed
  __builtin_amdgcn_s_barrier();

  // ---- fragment ds_read addressing ----
  const int q4 = lane >> 4;
  const int sx = lane & 7;              // == frag_row & 7 (bases are mult of 16)
  const int sk0 = (q4 ^ sx) * 8;        // kstep0 slot (u16 off)
  const int sk1 = sk0 ^ 32;             // kstep1 slot: (s^4)*8
  const int aOff = (wm * 64 + (lane & 15)) * 64;
  const int bOff = (wn * 64 + (lane & 15)) * 64;

  f32x4 acc[4][4];
  #pragma unroll
  for (int i = 0; i < 4; i++)
    #pragma unroll
    for (int j = 0; j < 4; j++) acc[i][j] = (f32x4){0.f, 0.f, 0.f, 0.f};

  int kk = 128;                          // stages during tile t are for tile t+2
  for (int t = 0; t < T; ++t) {
    const int cb = t & 1;
    const u16* LA = SM + cb * 8192;
    const u16* LB = SM + 16384 + cb * 16384;
    u16* sLA = SM + cb * 8192;           // tile t+2 -> same-parity buffer
    u16* sLB = SM + 16384 + cb * 16384;
    s8bf af[4][2], bf[4][2];

    // ---- P0: 12 reads (A m0-3 both ks, B n0-1 both ks) -> bar -> 16 MFMA ----
    #pragma unroll
    for (int m = 0; m < 4; m++) {
      af[m][0] = *(const s8bf*)&LA[aOff + m * 1024 + sk0];
      af[m][1] = *(const s8bf*)&LA[aOff + m * 1024 + sk1];
    }
    #pragma unroll
    for (int n = 0; n < 2; n++) {
      bf[n][0] = *(const s8bf*)&LB[bOff + n * 1024 + sk0];
      bf[n][1] = *(const s8bf*)&LB[bOff + n * 1024 + sk1];
    }
    __builtin_amdgcn_sched_barrier(0);
    __builtin_amdgcn_s_barrier();
    __builtin_amdgcn_s_setprio(1);
    #pragma unroll
    for (int ks = 0; ks < 2; ks++)
      #pragma unroll
      for (int m = 0; m < 4; m++)
        #pragma unroll
        for (int n = 0; n < 2; n++)
          acc[m][n] = __builtin_amdgcn_mfma_f32_16x16x32_bf16(af[m][ks], bf[n][ks],
                                                              acc[m][n], 0, 0, 0);
    __builtin_amdgcn_s_setprio(0);
    __builtin_amdgcn_s_barrier();

    // ---- P1: 4 reads (B n2-3 both ks) -> bar -> 16 MFMA -> lgkm(0) -> bar ----
    #pragma unroll
    for (int n = 2; n < 4; n++) {
      bf[n][0] = *(const s8bf*)&LB[bOff + n * 1024 + sk0];
      bf[n][1] = *(const s8bf*)&LB[bOff + n * 1024 + sk1];
    }
    __builtin_amdgcn_sched_barrier(0);
    __builtin_amdgcn_s_barrier();
    __builtin_amdgcn_s_setprio(1);
    #pragma unroll
    for (int ks = 0; ks < 2; ks++)
      #pragma unroll
      for (int m = 0; m < 4; m++)
        #pragma unroll
        for (int n = 2; n < 4; n++)
          acc[m][n] = __builtin_amdgcn_mfma_f32_16x16x32_bf16(af[m][ks], bf[n][ks],
                                                              acc[m][n], 0, 0, 0);
    __builtin_amdgcn_s_setprio(0);
    asm volatile("s_waitcnt lgkmcnt(0)" ::: "memory");  // all buf-cb reads done
    __builtin_amdgcn_sched_barrier(0);
    __builtin_amdgcn_s_barrier();                       // ...across all waves

    // ---- ST: stage tile t+2 into buf cb; wait tile t+1's loads; bar ----
    if (t + 2 < T) {
      gl_lds16(aB[0] + kk, sLA + wb * 8);
      gl_lds16(aB[1] + kk, sLA + (512 + wb) * 8);
      gl_lds16(bB[0] + kk, sLB + wb * 8);
      gl_lds16(bB[1] + kk, sLB + (512 + wb) * 8);
      gl_lds16(bB[2] + kk, sLB + (1024 + wb) * 8);
      gl_lds16(bB[3] + kk, sLB + (1536 + wb) * 8);
    }
    __builtin_amdgcn_sched_barrier(0);
    if (t < T - 2)       asm volatile("s_waitcnt vmcnt(6)" ::: "memory");
    else if (t == T - 2) asm volatile("s_waitcnt vmcnt(0)" ::: "memory");
    if (t < T - 1) {
      __builtin_amdgcn_sched_barrier(0);
      __builtin_amdgcn_s_barrier();
    }
    kk += 64;
  }

  // ---- epilogue: 4 rounds over m-frags; 32 rows x 256 cols per round via LDS ----
  #pragma unroll
  for (int m = 0; m < 4; m++) {
    __syncthreads();
    const int rbase = wm * 16 + ((lane >> 4) << 2);
    #pragma unroll
    for (int n = 0; n < 4; n++) {
      const int lcol = wn * 64 + n * 16 + colq;
      #pragma unroll
      for (int r = 0; r < 4; r++) {
        float v = acc[m][n][r] + bv[n];
        if (MODE == 1) v = fmaxf(v, 0.f);
        SM[(rbase + r) * 264 + lcol] = f2b(v);
      }
    }
    __syncthreads();
    #pragma unroll
    for (int it = 0; it < 2; it++) {
      const int idx = it * 512 + tid;
      const int rl = idx >> 5;
      const int c16 = (idx & 31) * 8;
      const int grow = (rl < 16) ? (m * 16 + rl) : (48 + m * 16 + rl);
      uint4 v = *(const uint4*)&SM[rl * 264 + c16];
      *(uint4*)&Hout[(size_t)(slot0 + grow) * N + n0 + c16] = v;
    }
  }
}

// ---- combine: out[t] = w0*y[s0] + w1*y[s1] (y bf16, out fp32) ----
__global__ __launch_bounds__(256) void combine_kernel(
    const u16* __restrict__ y, const int* __restrict__ sot,
    const float* __restrict__ tkw, float* __restrict__ out) {
  int wave = threadIdx.x >> 6, lane = threadIdx.x & 63;
  int t = blockIdx.x * 4 + wave;
  int s0 = sot[t * 2], s1 = sot[t * 2 + 1];
  float w0 = tkw[t * 2], w1 = tkw[t * 2 + 1];
  const u16* y0 = y + (size_t)s0 * DIM;
  const u16* y1 = y + (size_t)s1 * DIM;
  float* op = out + (size_t)t * DIM;
  #pragma unroll
  for (int i = 0; i < 4; i++) {
    int d = i * 256 + lane * 4;
    uint2 a = *(const uint2*)(y0 + d);
    uint2 b = *(const uint2*)(y1 + d);
    float4 o;
    o.x = w0 * b2f((u16)(a.x & 0xFFFF)) + w1 * b2f((u16)(b.x & 0xFFFF));
    o.y = w0 * b2f((u16)(a.x >> 16))    + w1 * b2f((u16)(b.x >> 16));
    o.z = w0 * b2f((u16)(a.y & 0xFFFF)) + w1 * b2f((u16)(b.y & 0xFFFF));
    o.w = w0 * b2f((u16)(a.y >> 16))    + w1 * b2f((u16)(b.y >> 16));
    *(float4*)(op + d) = o;
  }
}

extern "C" void kernel_launch(void* const* d_in, const int* in_sizes, int n_in,
                              void* d_out, int out_size, void* d_ws, size_t ws_size,
                              hipStream_t stream) {
  const float* x  = (const float*)d_in[0];
  const float* Wr = (const float*)d_in[1];
  const float* br = (const float*)d_in[2];
  const float* W1 = (const float*)d_in[3];
  const float* b1 = (const float*)d_in[4];
  const float* W2 = (const float*)d_in[5];
  const float* b2 = (const float*)d_in[6];
  float* out = (float*)d_out;
  char* ws = (char*)d_ws;

  u16*   W1t  = (u16*)(ws + OFF_W1T);
  u16*   W2t  = (u16*)(ws + OFF_W2T);
  u16*   ybuf = (u16*)(ws + OFF_Y);     // overlays W1t (dead after GEMM1)
  u16*   xb   = (u16*)(ws + OFF_XB);
  u16*   hbuf = (u16*)(ws + OFF_H);
  int*   tos  = (int*)(ws + OFF_TOS);
  int*   sot  = (int*)(ws + OFF_SOT);
  int*   tki  = (int*)(ws + OFF_TKI);
  float* tkw  = (float*)(ws + OFF_TKW);
  int*   cnt  = (int*)(ws + OFF_CNT);
  int*   pof  = (int*)(ws + OFF_POF);
  int*   cur  = (int*)(ws + OFF_CUR);
  int*   nt   = (int*)(ws + OFF_NT);
  int*   te   = (int*)(ws + OFF_TE);
  int*   ts   = (int*)(ws + OFF_TS);

  hipMemsetAsync(tos, 0xFF, (size_t)MAX_SLOTS * sizeof(int), stream);  // -1
  hipMemsetAsync(cnt, 0, 8 * sizeof(int), stream);

  // tiles: NE * (R/256) * (C/64)
  transpose_to_bf16<<<dim3(NE * (DIM / 256) * (HID / 64)), 256, 0, stream>>>(W1, W1t, DIM, HID);
  transpose_to_bf16<<<dim3(NE * (HID / 256) * (DIM / 64)), 256, 0, stream>>>(W2, W2t, HID, DIM);
  convert_x<<<dim3(N_TOK * DIM / (256 * 8)), 256, 0, stream>>>(x, xb);
  router_kernel<<<dim3(N_TOK / 4), 256, 0, stream>>>(x, Wr, br, tki, tkw, cnt);
  plan_kernel<<<dim3(1), 64, 0, stream>>>(cnt, pof, cur, nt, te, ts);
  scatter_kernel<<<dim3(N_TOK / 256), 256, 0, stream>>>(tki, pof, cur, tos, sot);

  // 128x256 tiles; n-block fastest -> XCD-stationary B stripes
  moe_gemm<1><<<dim3((MAX_SLOTS / 128) * (HID / 256)), 512, 0, stream>>>(
      xb, W1t, b1, hbuf, te, ts, nt, tos, DIM, HID, HID / 256);
  moe_gemm<2><<<dim3((MAX_SLOTS / 128) * (DIM / 256)), 512, 0, stream>>>(
      hbuf, W2t, b2, ybuf, te, ts, nt, tos, HID, DIM, DIM / 256);
  combine_kernel<<<dim3(N_TOK / 4), 256, 0, stream>>>(ybuf, sot, tkw, out);
}

// Round 3
// 959.360 us; speedup vs baseline: 1.0927x; 1.0927x over previous
//
#include <hip/hip_runtime.h>
#include <stdint.h>

typedef unsigned short u16;
typedef __attribute__((ext_vector_type(8))) short s8bf;   // 8 bf16 in 4 VGPRs
typedef __attribute__((ext_vector_type(4))) float f32x4;

#define N_TOK 8192
#define DIM   1024
#define HID   4096
#define NE    8
#define MAX_SLOTS 17408   // 16384 + 8*128 worst-case padding
#define MAX_TILES 160
#define TSTR  264         // transpose LDS row stride (u16): 528B, 16B-aligned
#define LSTR  152         // GEMM epilogue LDS row stride (u16): 304B, 16B-aligned

// ---- workspace layout (bytes) ----
#define OFF_W1T  ((size_t)0)                    // [E][HID][DIM] bf16  (n-major, k-contig)
#define OFF_Y    ((size_t)0)                    // y bf16 [MAX_SLOTS][DIM] — overlays dead W1T
#define OFF_W2T  ((size_t)67108864)             // [E][DIM][HID] bf16
#define OFF_XB   ((size_t)134217728)            // [N_TOK][DIM] bf16
#define OFF_H    ((size_t)150994944)            // [MAX_SLOTS][HID] bf16
#define OFF_TOS  ((size_t)293601280)            // token_of_slot int[MAX_SLOTS]
#define OFF_SOT  ((size_t)293670912)            // slot_of_token int[N_TOK*2]
#define OFF_TKI  ((size_t)293740544)            // topk idx int[N_TOK*2]
#define OFF_TKW  ((size_t)293806080)            // topk w  float[N_TOK*2]
#define OFF_CNT  ((size_t)293871616)            // counts int[8]
#define OFF_POF  ((size_t)293871680)            // padded offsets int[8]
#define OFF_CUR  ((size_t)293871744)            // cursors int[8]
#define OFF_NT   ((size_t)293871808)            // n_tiles int[1]
#define OFF_TE   ((size_t)293871872)            // tile_expert int[MAX_TILES]
#define OFF_TS   ((size_t)293872896)            // tile_slot0  int[MAX_TILES]

__device__ __forceinline__ u16 f2b(float v) {   // fp32 -> bf16 RNE
  union { float f; uint32_t u; } c; c.f = v;
  uint32_t u = c.u;
  return (u16)((u + 0x7FFFu + ((u >> 16) & 1u)) >> 16);
}
__device__ __forceinline__ float b2f(u16 b) {
  union { uint32_t u; float f; } c; c.u = ((uint32_t)b) << 16; return c.f;
}

// async global->LDS DMA, 16 B per lane. lds ptr wave-uniform; lane i -> l + i*16.
typedef const __attribute__((address_space(1))) uint32_t* gp32;
typedef __attribute__((address_space(3))) uint32_t* lp32;
__device__ __forceinline__ void gl_lds16(const u16* g, u16* l) {
  __builtin_amdgcn_global_load_lds((gp32)(const void*)g, (lp32)(void*)l, 16, 0, 0);
}

// ---- fused fp32 [R][C] -> bf16 [C][R] transpose, 256(R) x 64(C) tiles ----
__global__ __launch_bounds__(256) void transpose_to_bf16(
    const float* __restrict__ in, u16* __restrict__ out, int R, int C) {
  __shared__ u16 L[64 * TSTR];   // 33792 B
  int tiles_c = C >> 6, tiles_r = R >> 8;
  int per = tiles_c * tiles_r;
  int e = blockIdx.x / per, t = blockIdx.x % per;
  int tr = t / tiles_c, tc = t % tiles_c;
  const float* ip = in + (size_t)e * R * C + (size_t)(tr * 256) * C + tc * 64;
  u16* op = out + (size_t)e * R * C + (size_t)(tc * 64) * R + tr * 256;
  const int tid = threadIdx.x;
  const int c = tid & 63;
  const int rb0 = (tid >> 6) * 8;
  #pragma unroll
  for (int p = 0; p < 8; p++) {
    int rb = p * 32 + rb0;
    u16 tmp[8];
    #pragma unroll
    for (int j = 0; j < 8; j++) tmp[j] = f2b(ip[(size_t)(rb + j) * C + c]);
    *(uint4*)&L[c * TSTR + rb] = *(const uint4*)tmp;
  }
  __syncthreads();
  const int s = tid & 31, ocb = tid >> 5;
  #pragma unroll
  for (int p = 0; p < 8; p++) {
    int oc = p * 8 + ocb;
    uint4 v = *(const uint4*)&L[oc * TSTR + s * 8];
    *(uint4*)&op[(size_t)oc * R + s * 8] = v;
  }
}

// ---- x fp32 -> bf16 ----
__global__ __launch_bounds__(256) void convert_x(const float* __restrict__ x,
                                                 u16* __restrict__ xb) {
  size_t i = ((size_t)blockIdx.x * 256 + threadIdx.x) * 8;
  float4 v0 = *(const float4*)(x + i);
  float4 v1 = *(const float4*)(x + i + 4);
  u16 o[8] = {f2b(v0.x), f2b(v0.y), f2b(v0.z), f2b(v0.w),
              f2b(v1.x), f2b(v1.y), f2b(v1.z), f2b(v1.w)};
  *(uint4*)(xb + i) = *(const uint4*)o;
}

// ---- router: logits -> top2 -> renormalized weights (fp32). one wave/token ----
__global__ __launch_bounds__(256) void router_kernel(
    const float* __restrict__ x, const float* __restrict__ Wr,
    const float* __restrict__ br, int* __restrict__ tki, float* __restrict__ tkw,
    int* __restrict__ counts) {
  int wave = threadIdx.x >> 6, lane = threadIdx.x & 63;
  int t = blockIdx.x * 4 + wave;
  const float* xr = x + (size_t)t * DIM;
  float acc[8] = {0.f, 0.f, 0.f, 0.f, 0.f, 0.f, 0.f, 0.f};
  #pragma unroll
  for (int i = 0; i < 16; i++) {
    int d = lane + i * 64;
    float xv = xr[d];
    float4 wa = *(const float4*)(Wr + d * 8);
    float4 wb = *(const float4*)(Wr + d * 8 + 4);
    acc[0] += xv * wa.x; acc[1] += xv * wa.y; acc[2] += xv * wa.z; acc[3] += xv * wa.w;
    acc[4] += xv * wb.x; acc[5] += xv * wb.y; acc[6] += xv * wb.z; acc[7] += xv * wb.w;
  }
  #pragma unroll
  for (int e = 0; e < 8; e++)
    #pragma unroll
    for (int off = 32; off >= 1; off >>= 1)
      acc[e] += __shfl_xor(acc[e], off, 64);
  if (lane == 0) {
    float l[8];
    #pragma unroll
    for (int e = 0; e < 8; e++) l[e] = acc[e] + br[e];
    float l0 = -1e30f; int i0 = 0;
    #pragma unroll
    for (int e = 0; e < 8; e++) if (l[e] > l0) { l0 = l[e]; i0 = e; }
    float l1 = -1e30f; int i1 = 0;
    #pragma unroll
    for (int e = 0; e < 8; e++) if (e != i0 && l[e] > l1) { l1 = l[e]; i1 = e; }
    float w0 = 1.f / (1.f + expf(l1 - l0));
    tki[t * 2] = i0; tki[t * 2 + 1] = i1;
    tkw[t * 2] = w0; tkw[t * 2 + 1] = 1.f - w0;
    atomicAdd(&counts[i0], 1);
    atomicAdd(&counts[i1], 1);
  }
}

// ---- plan: padded per-expert offsets + tile list (parallel over experts) ----
__global__ void plan_kernel(const int* __restrict__ counts, int* __restrict__ poff,
                            int* __restrict__ cursor, int* __restrict__ ntiles,
                            int* __restrict__ tile_e, int* __restrict__ tile_s0) {
  int e = threadIdx.x;
  if (e < NE) {
    int po = 0, tb = 0;
    for (int i = 0; i < e; i++) {
      int tl = (counts[i] + 127) >> 7;
      po += tl << 7; tb += tl;
    }
    poff[e] = po;
    cursor[e] = 0;
    int tl = (counts[e] + 127) >> 7;
    for (int j = 0; j < tl; j++) { tile_e[tb + j] = e; tile_s0[tb + j] = po + j * 128; }
    if (e == NE - 1) ntiles[0] = tb + tl;
  }
}

// ---- scatter tokens into per-expert slots ----
__global__ __launch_bounds__(256) void scatter_kernel(
    const int* __restrict__ tki, const int* __restrict__ poff,
    int* __restrict__ cursor, int* __restrict__ token_of_slot,
    int* __restrict__ slot_of_token) {
  int t = blockIdx.x * 256 + threadIdx.x;
  #pragma unroll
  for (int k = 0; k < 2; k++) {
    int e = tki[t * 2 + k];
    int r = atomicAdd(&cursor[e], 1);
    int s = poff[e] + r;
    token_of_slot[s] = t;
    slot_of_token[t * 2 + k] = s;
  }
}

// ---- grouped GEMM: C[128x128]/block, 4 waves (2Mx2N), 16x16x32 bf16 MFMA ----
// Pipeline (round-1 structure, kept): per 64-K tile
//   P0: 12 ds_read_b128 -> bar -> 16 MFMA -> bar
//   P1:  4 ds_read_b128 -> bar -> 16 MFMA -> lgkmcnt(0) -> bar
//   ST:  8 global_load_lds (tile t+2, same-parity buffer); vmcnt(8) waits
//        tile t+1's 8 loads; bar.  Depth-2 prefetch, counted vmcnt.
// THIS ROUND'S variable: 64 KB LDS -> 2 blocks/CU co-resident (was 96 KB, 1
// block/CU). Cross-block overlap hides barrier drains / prologue / epilogue
// (m114: MFMA+VALU pipes of independent waves co-schedule).
// T2 swizzle unchanged: LDS linear; global SOURCE column inverse-permuted by
// (row&7); fragment ds_read applies the same XOR.
// MODE 1: A rows gathered via token_of_slot, relu(acc+b1) -> h
// MODE 2: A rows = slots (h),               (acc+b2)      -> y
template <int MODE>
__global__ __launch_bounds__(256, 2) void moe_gemm(
    const u16* __restrict__ A, const u16* __restrict__ Bt,
    const float* __restrict__ bias, u16* __restrict__ Hout,
    const int* __restrict__ tile_e, const int* __restrict__ tile_s0,
    const int* __restrict__ ntiles, const int* __restrict__ token_of_slot,
    int K, int N, int NB) {
  __shared__ u16 SM[32768];   // 64 KB: A0@0, A1@8192, B0@16384, B1@24576 (u16 units)

  const int nblk = blockIdx.x % NB;     // n fastest -> XCD-stationary B stripes
  const int tileid = blockIdx.x / NB;
  if (tileid >= ntiles[0]) return;
  const int e = tile_e[tileid];
  const int slot0 = tile_s0[tileid];
  const int n0 = nblk * 128;
  const int T = K >> 6;                 // 64-K tiles

  const int tid = threadIdx.x;
  const int lane = tid & 63;
  const int wave = tid >> 6;            // 0..3
  const int wm = wave >> 1;             // 0..1 : 64-row M half
  const int wn = wave & 1;              // 0..1 : 64-col N half

  // ---- staging source pointers (inverse-swizzled global columns) ----
  // site s covers rows s*32..s*32+31; thread -> row s*32+(tid>>3), slot tid&7
  const int srow = tid >> 3;
  const int sslot = tid & 7;
  const u16* aB[4];
  const u16* bB[4];
  #pragma unroll
  for (int s = 0; s < 4; s++) {
    int row = s * 32 + srow;
    int scol = (sslot ^ (row & 7)) * 8;
    int arow;
    if (MODE == 1) { int t0 = token_of_slot[slot0 + row]; arow = t0 < 0 ? 0 : t0; }
    else arow = slot0 + row;
    aB[s] = A + (size_t)arow * K + scol;
  }
  const u16* bE = Bt + (size_t)e * N * K;
  #pragma unroll
  for (int s = 0; s < 4; s++) {
    int row = s * 32 + srow;
    int scol = (sslot ^ (row & 7)) * 8;
    bB[s] = bE + (size_t)(n0 + row) * K + scol;
  }

  // bias preload BEFORE stages + vmcnt(0) pin, so in-loop vmcnt counts are exact
  const int colq = lane & 15;
  float bv[4];
  #pragma unroll
  for (int n = 0; n < 4; n++) bv[n] = bias[(size_t)e * N + n0 + wn * 64 + n * 16 + colq];
  asm volatile("s_waitcnt vmcnt(0)" ::: "memory");

  const int wo = wave * 512;            // u16: wave's 1 KB slice within a site
  // ---- prologue: stage K-tiles 0 and 1 (8 loads each, in order) ----
  #pragma unroll
  for (int tt = 0; tt < 2; tt++) {
    const int kq = tt * 64;
    u16* LA = SM + tt * 8192;
    u16* LB = SM + 16384 + tt * 8192;
    #pragma unroll
    for (int s = 0; s < 4; s++) gl_lds16(aB[s] + kq, LA + s * 2048 + wo);
    #pragma unroll
    for (int s = 0; s < 4; s++) gl_lds16(bB[s] + kq, LB + s * 2048 + wo);
  }
  asm volatile("s_waitcnt vmcnt(8)" ::: "memory");   // tile0 landed
  __builtin_amdgcn_s_barrier();

  // ---- fragment ds_read addressing ----
  const int q4 = lane >> 4;
  const int sx = lane & 7;              // == frag_row & 7 (bases are mult of 16)
  const int sk0 = (q4 ^ sx) * 8;        // kstep0 slot (u16 off)
  const int sk1 = sk0 ^ 32;             // kstep1 slot: (s^4)*8
  const int aOff = (wm * 64 + (lane & 15)) * 64;
  const int bOff = (wn * 64 + (lane & 15)) * 64;

  f32x4 acc[4][4];
  #pragma unroll
  for (int i = 0; i < 4; i++)
    #pragma unroll
    for (int j = 0; j < 4; j++) acc[i][j] = (f32x4){0.f, 0.f, 0.f, 0.f};

  int kk = 128;                          // stages during tile t are for tile t+2
  for (int t = 0; t < T; ++t) {
    const int cb = t & 1;
    const u16* LA = SM + cb * 8192;
    const u16* LB = SM + 16384 + cb * 8192;
    u16* sLA = SM + cb * 8192;           // tile t+2 -> same-parity buffer
    u16* sLB = SM + 16384 + cb * 8192;
    s8bf af[4][2], bf[4][2];

    // ---- P0: 12 reads (A m0-3 both ks, B n0-1 both ks) -> bar -> 16 MFMA ----
    #pragma unroll
    for (int m = 0; m < 4; m++) {
      af[m][0] = *(const s8bf*)&LA[aOff + m * 1024 + sk0];
      af[m][1] = *(const s8bf*)&LA[aOff + m * 1024 + sk1];
    }
    #pragma unroll
    for (int n = 0; n < 2; n++) {
      bf[n][0] = *(const s8bf*)&LB[bOff + n * 1024 + sk0];
      bf[n][1] = *(const s8bf*)&LB[bOff + n * 1024 + sk1];
    }
    __builtin_amdgcn_sched_barrier(0);
    __builtin_amdgcn_s_barrier();
    __builtin_amdgcn_s_setprio(1);
    #pragma unroll
    for (int ks = 0; ks < 2; ks++)
      #pragma unroll
      for (int m = 0; m < 4; m++)
        #pragma unroll
        for (int n = 0; n < 2; n++)
          acc[m][n] = __builtin_amdgcn_mfma_f32_16x16x32_bf16(af[m][ks], bf[n][ks],
                                                              acc[m][n], 0, 0, 0);
    __builtin_amdgcn_s_setprio(0);
    __builtin_amdgcn_s_barrier();

    // ---- P1: 4 reads (B n2-3 both ks) -> bar -> 16 MFMA -> lgkm(0) -> bar ----
    #pragma unroll
    for (int n = 2; n < 4; n++) {
      bf[n][0] = *(const s8bf*)&LB[bOff + n * 1024 + sk0];
      bf[n][1] = *(const s8bf*)&LB[bOff + n * 1024 + sk1];
    }
    __builtin_amdgcn_sched_barrier(0);
    __builtin_amdgcn_s_barrier();
    __builtin_amdgcn_s_setprio(1);
    #pragma unroll
    for (int ks = 0; ks < 2; ks++)
      #pragma unroll
      for (int m = 0; m < 4; m++)
        #pragma unroll
        for (int n = 2; n < 4; n++)
          acc[m][n] = __builtin_amdgcn_mfma_f32_16x16x32_bf16(af[m][ks], bf[n][ks],
                                                              acc[m][n], 0, 0, 0);
    __builtin_amdgcn_s_setprio(0);
    asm volatile("s_waitcnt lgkmcnt(0)" ::: "memory");  // all buf-cb reads done
    __builtin_amdgcn_sched_barrier(0);
    __builtin_amdgcn_s_barrier();                       // ...across all waves

    // ---- ST: stage tile t+2 into buf cb; wait tile t+1's loads; bar ----
    if (t + 2 < T) {
      #pragma unroll
      for (int s = 0; s < 4; s++) gl_lds16(aB[s] + kk, sLA + s * 2048 + wo);
      #pragma unroll
      for (int s = 0; s < 4; s++) gl_lds16(bB[s] + kk, sLB + s * 2048 + wo);
    }
    __builtin_amdgcn_sched_barrier(0);
    if (t < T - 2)       asm volatile("s_waitcnt vmcnt(8)" ::: "memory");
    else if (t == T - 2) asm volatile("s_waitcnt vmcnt(0)" ::: "memory");
    if (t < T - 1) {
      __builtin_amdgcn_sched_barrier(0);
      __builtin_amdgcn_s_barrier();
    }
    kk += 64;
  }

  // ---- epilogue: stage 128x128 bf16 in LDS, stream out coalesced b128 rows ----
  __syncthreads();
  const int rq = (lane >> 4) * 4;
  #pragma unroll
  for (int nt = 0; nt < 4; nt++) {
    int lcol = wn * 64 + nt * 16 + colq;
    #pragma unroll
    for (int mt = 0; mt < 4; mt++) {
      int rowbase = wm * 64 + mt * 16 + rq;
      #pragma unroll
      for (int r = 0; r < 4; r++) {
        float v = acc[mt][nt][r] + bv[nt];
        if (MODE == 1) v = fmaxf(v, 0.f);
        SM[(rowbase + r) * LSTR + lcol] = f2b(v);
      }
    }
  }
  __syncthreads();
  #pragma unroll
  for (int k = 0; k < 8; k++) {
    int ch = k * 256 + tid;
    int row = ch >> 4;
    int cp = (ch & 15) * 8;
    uint4 v = *(const uint4*)&SM[row * LSTR + cp];
    *(uint4*)&Hout[(size_t)(slot0 + row) * N + n0 + cp] = v;
  }
}

// ---- combine: out[t] = w0*y[s0] + w1*y[s1] (y bf16, out fp32) ----
__global__ __launch_bounds__(256) void combine_kernel(
    const u16* __restrict__ y, const int* __restrict__ sot,
    const float* __restrict__ tkw, float* __restrict__ out) {
  int wave = threadIdx.x >> 6, lane = threadIdx.x & 63;
  int t = blockIdx.x * 4 + wave;
  int s0 = sot[t * 2], s1 = sot[t * 2 + 1];
  float w0 = tkw[t * 2], w1 = tkw[t * 2 + 1];
  const u16* y0 = y + (size_t)s0 * DIM;
  const u16* y1 = y + (size_t)s1 * DIM;
  float* op = out + (size_t)t * DIM;
  #pragma unroll
  for (int i = 0; i < 4; i++) {
    int d = i * 256 + lane * 4;
    uint2 a = *(const uint2*)(y0 + d);
    uint2 b = *(const uint2*)(y1 + d);
    float4 o;
    o.x = w0 * b2f((u16)(a.x & 0xFFFF)) + w1 * b2f((u16)(b.x & 0xFFFF));
    o.y = w0 * b2f((u16)(a.x >> 16))    + w1 * b2f((u16)(b.x >> 16));
    o.z = w0 * b2f((u16)(a.y & 0xFFFF)) + w1 * b2f((u16)(b.y & 0xFFFF));
    o.w = w0 * b2f((u16)(a.y >> 16))    + w1 * b2f((u16)(b.y >> 16));
    *(float4*)(op + d) = o;
  }
}

extern "C" void kernel_launch(void* const* d_in, const int* in_sizes, int n_in,
                              void* d_out, int out_size, void* d_ws, size_t ws_size,
                              hipStream_t stream) {
  const float* x  = (const float*)d_in[0];
  const float* Wr = (const float*)d_in[1];
  const float* br = (const float*)d_in[2];
  const float* W1 = (const float*)d_in[3];
  const float* b1 = (const float*)d_in[4];
  const float* W2 = (const float*)d_in[5];
  const float* b2 = (const float*)d_in[6];
  float* out = (float*)d_out;
  char* ws = (char*)d_ws;

  u16*   W1t  = (u16*)(ws + OFF_W1T);
  u16*   W2t  = (u16*)(ws + OFF_W2T);
  u16*   ybuf = (u16*)(ws + OFF_Y);     // overlays W1t (dead after GEMM1)
  u16*   xb   = (u16*)(ws + OFF_XB);
  u16*   hbuf = (u16*)(ws + OFF_H);
  int*   tos  = (int*)(ws + OFF_TOS);
  int*   sot  = (int*)(ws + OFF_SOT);
  int*   tki  = (int*)(ws + OFF_TKI);
  float* tkw  = (float*)(ws + OFF_TKW);
  int*   cnt  = (int*)(ws + OFF_CNT);
  int*   pof  = (int*)(ws + OFF_POF);
  int*   cur  = (int*)(ws + OFF_CUR);
  int*   nt   = (int*)(ws + OFF_NT);
  int*   te   = (int*)(ws + OFF_TE);
  int*   ts   = (int*)(ws + OFF_TS);

  hipMemsetAsync(tos, 0xFF, (size_t)MAX_SLOTS * sizeof(int), stream);  // -1
  hipMemsetAsync(cnt, 0, 8 * sizeof(int), stream);

  // tiles: NE * (R/256) * (C/64)
  transpose_to_bf16<<<dim3(NE * (DIM / 256) * (HID / 64)), 256, 0, stream>>>(W1, W1t, DIM, HID);
  transpose_to_bf16<<<dim3(NE * (HID / 256) * (DIM / 64)), 256, 0, stream>>>(W2, W2t, HID, DIM);
  convert_x<<<dim3(N_TOK * DIM / (256 * 8)), 256, 0, stream>>>(x, xb);
  router_kernel<<<dim3(N_TOK / 4), 256, 0, stream>>>(x, Wr, br, tki, tkw, cnt);
  plan_kernel<<<dim3(1), 64, 0, stream>>>(cnt, pof, cur, nt, te, ts);
  scatter_kernel<<<dim3(N_TOK / 256), 256, 0, stream>>>(tki, pof, cur, tos, sot);

  // 128x128 tiles; n-block fastest -> XCD-stationary B stripes; 2 blocks/CU
  moe_gemm<1><<<dim3((MAX_SLOTS / 128) * (HID / 128)), 256, 0, stream>>>(
      xb, W1t, b1, hbuf, te, ts, nt, tos, DIM, HID, HID / 128);
  moe_gemm<2><<<dim3((MAX_SLOTS / 128) * (DIM / 128)), 256, 0, stream>>>(
      hbuf, W2t, b2, ybuf, te, ts, nt, tos, HID, DIM, DIM / 128);
  combine_kernel<<<dim3(N_TOK / 4), 256, 0, stream>>>(ybuf, sot, tkw, out);
}

// Round 4
// 886.890 us; speedup vs baseline: 1.1820x; 1.0817x over previous
//
#include <hip/hip_runtime.h>
#include <stdint.h>

typedef unsigned short u16;
typedef __attribute__((ext_vector_type(8))) short s8bf;   // 8 bf16 in 4 VGPRs
typedef __attribute__((ext_vector_type(4))) float f32x4;

#define N_TOK 8192
#define DIM   1024
#define HID   4096
#define NE    8
#define MAX_SLOTS 17408   // 16384 + 8*128 worst-case padding
#define MAX_TILES 160
#define T2STR 272         // transpose LDS row stride (u16): 544B = 34x16B, b128-aligned
#define LSTR  152         // GEMM epilogue LDS row stride (u16): 304B, 16B-aligned

// ---- workspace layout (bytes) ----
#define OFF_W1T  ((size_t)0)                    // [E][HID][DIM] bf16  (n-major, k-contig)
#define OFF_Y    ((size_t)0)                    // y bf16 [MAX_SLOTS][DIM] — overlays dead W1T
#define OFF_W2T  ((size_t)67108864)             // [E][DIM][HID] bf16
#define OFF_XB   ((size_t)134217728)            // [N_TOK][DIM] bf16
#define OFF_H    ((size_t)150994944)            // [MAX_SLOTS][HID] bf16
#define OFF_TOS  ((size_t)293601280)            // token_of_slot int[MAX_SLOTS]
#define OFF_SOT  ((size_t)293670912)            // slot_of_token int[N_TOK*2]
#define OFF_TKI  ((size_t)293740544)            // topk idx int[N_TOK*2]
#define OFF_TKW  ((size_t)293806080)            // topk w  float[N_TOK*2]
#define OFF_CNT  ((size_t)293871616)            // counts int[8]
#define OFF_POF  ((size_t)293871680)            // padded offsets int[8]
#define OFF_CUR  ((size_t)293871744)            // cursors int[8]
#define OFF_NT   ((size_t)293871808)            // n_tiles int[1]
#define OFF_TE   ((size_t)293871872)            // tile_expert int[MAX_TILES]
#define OFF_TS   ((size_t)293872896)            // tile_slot0  int[MAX_TILES]

__device__ __forceinline__ u16 f2b(float v) {   // fp32 -> bf16 RNE
  union { float f; uint32_t u; } c; c.f = v;
  uint32_t u = c.u;
  return (u16)((u + 0x7FFFu + ((u >> 16) & 1u)) >> 16);
}
__device__ __forceinline__ float b2f(u16 b) {
  union { uint32_t u; float f; } c; c.u = ((uint32_t)b) << 16; return c.f;
}

// async global->LDS DMA, 16 B per lane. lds ptr wave-uniform; lane i -> l + i*16.
typedef const __attribute__((address_space(1))) uint32_t* gp32;
typedef __attribute__((address_space(3))) uint32_t* lp32;
__device__ __forceinline__ void gl_lds16(const u16* g, u16* l) {
  __builtin_amdgcn_global_load_lds((gp32)(const void*)g, (lp32)(void*)l, 16, 0, 0);
}

// ---- fused fp32 [R][C] -> bf16 [C][R] transpose, 256(R) x 64(C) tiles ----
// v2: float4 global loads (16 VMEM/thread, was 64 scalar dwords), register 4x4
// column-pack -> ds_write_b64 (4-way bank, 1.58x, 16 instrs), b128 LDS reads
// (2-way, free) -> 256B-coalesced b128 stores. ~250 instr/thread (was ~390);
// this kernel is issue-bound, not BW-bound.
__global__ __launch_bounds__(256) void transpose_to_bf16(
    const float* __restrict__ in, u16* __restrict__ out, int R, int C) {
  __shared__ u16 L[64 * T2STR];   // 34816 B
  int tiles_c = C >> 6, tiles_r = R >> 8;
  int per = tiles_c * tiles_r;
  int e = blockIdx.x / per, t = blockIdx.x % per;
  int tr = t / tiles_c, tc = t % tiles_c;
  const float* ip = in + (size_t)e * R * C + (size_t)(tr * 256) * C + tc * 64;
  u16* op = out + (size_t)e * R * C + (size_t)(tc * 64) * R + tr * 256;
  const int tid = threadIdx.x;

  // phase 1: 4 passes; thread loads 4 float4 (4 consecutive rows x 4 cols),
  // packs each column into ushort4 -> ds_write_b64 at L[col][row-quad].
  const int c4 = (tid & 15) * 4;        // col group (C-dim)
  const int rq = (tid >> 4) * 4;        // row quad within 64-row pass
  #pragma unroll
  for (int p = 0; p < 4; p++) {
    int r0 = p * 64 + rq;
    float4 v0 = *(const float4*)(ip + (size_t)(r0 + 0) * C + c4);
    float4 v1 = *(const float4*)(ip + (size_t)(r0 + 1) * C + c4);
    float4 v2 = *(const float4*)(ip + (size_t)(r0 + 2) * C + c4);
    float4 v3 = *(const float4*)(ip + (size_t)(r0 + 3) * C + c4);
    const float* f0 = (const float*)&v0;
    const float* f1 = (const float*)&v1;
    const float* f2 = (const float*)&v2;
    const float* f3 = (const float*)&v3;
    #pragma unroll
    for (int i = 0; i < 4; i++) {
      u16 w[4] = {f2b(f0[i]), f2b(f1[i]), f2b(f2[i]), f2b(f3[i])};
      *(uint2*)&L[(c4 + i) * T2STR + r0] = *(const uint2*)w;
    }
  }
  __syncthreads();

  // phase 2: 16 lanes per out-row -> 256B contiguous stores; 8 b128 reads+stores.
  const int oc0 = tid >> 4;             // 0..15
  const int ch  = tid & 15;
  #pragma unroll
  for (int jr = 0; jr < 4; jr++) {
    int oc = jr * 16 + oc0;
    #pragma unroll
    for (int h = 0; h < 2; h++) {
      int co = (ch + h * 16) * 8;       // u16 offset within row (0..255)
      uint4 v = *(const uint4*)&L[oc * T2STR + co];
      *(uint4*)&op[(size_t)oc * R + co] = v;
    }
  }
}

// ---- router + x->bf16 convert fused. one wave/token; identical load order to
// the old router (bit-identical logits), plus a 2B store per element for xb. ----
__global__ __launch_bounds__(256) void router_kernel(
    const float* __restrict__ x, const float* __restrict__ Wr,
    const float* __restrict__ br, u16* __restrict__ xb,
    int* __restrict__ tki, float* __restrict__ tkw, int* __restrict__ counts) {
  int wave = threadIdx.x >> 6, lane = threadIdx.x & 63;
  int t = blockIdx.x * 4 + wave;
  const float* xr = x + (size_t)t * DIM;
  u16* xo = xb + (size_t)t * DIM;
  float acc[8] = {0.f, 0.f, 0.f, 0.f, 0.f, 0.f, 0.f, 0.f};
  #pragma unroll
  for (int i = 0; i < 16; i++) {
    int d = lane + i * 64;
    float xv = xr[d];
    xo[d] = f2b(xv);                    // fused convert_x (128B/wave coalesced)
    float4 wa = *(const float4*)(Wr + d * 8);
    float4 wb = *(const float4*)(Wr + d * 8 + 4);
    acc[0] += xv * wa.x; acc[1] += xv * wa.y; acc[2] += xv * wa.z; acc[3] += xv * wa.w;
    acc[4] += xv * wb.x; acc[5] += xv * wb.y; acc[6] += xv * wb.z; acc[7] += xv * wb.w;
  }
  #pragma unroll
  for (int e = 0; e < 8; e++)
    #pragma unroll
    for (int off = 32; off >= 1; off >>= 1)
      acc[e] += __shfl_xor(acc[e], off, 64);
  if (lane == 0) {
    float l[8];
    #pragma unroll
    for (int e = 0; e < 8; e++) l[e] = acc[e] + br[e];
    float l0 = -1e30f; int i0 = 0;
    #pragma unroll
    for (int e = 0; e < 8; e++) if (l[e] > l0) { l0 = l[e]; i0 = e; }
    float l1 = -1e30f; int i1 = 0;
    #pragma unroll
    for (int e = 0; e < 8; e++) if (e != i0 && l[e] > l1) { l1 = l[e]; i1 = e; }
    float w0 = 1.f / (1.f + expf(l1 - l0));
    tki[t * 2] = i0; tki[t * 2 + 1] = i1;
    tkw[t * 2] = w0; tkw[t * 2 + 1] = 1.f - w0;
    atomicAdd(&counts[i0], 1);
    atomicAdd(&counts[i1], 1);
  }
}

// ---- plan: padded per-expert offsets + tile list + pad-slot tos init ----
__global__ void plan_kernel(const int* __restrict__ counts, int* __restrict__ poff,
                            int* __restrict__ cursor, int* __restrict__ ntiles,
                            int* __restrict__ tile_e, int* __restrict__ tile_s0,
                            int* __restrict__ tos) {
  __shared__ int spo[NE], scnt[NE];
  int tid = threadIdx.x;
  if (tid < NE) {
    int e = tid;
    int po = 0, tb = 0;
    for (int i = 0; i < e; i++) {
      int tl = (counts[i] + 127) >> 7;
      po += tl << 7; tb += tl;
    }
    poff[e] = po;
    cursor[e] = 0;
    spo[e] = po; scnt[e] = counts[e];
    int tl = (counts[e] + 127) >> 7;
    for (int j = 0; j < tl; j++) { tile_e[tb + j] = e; tile_s0[tb + j] = po + j * 128; }
    if (e == NE - 1) ntiles[0] = tb + tl;
  }
  __syncthreads();
  // pad slots get tos = -1 (was a separate hipMemsetAsync over all slots)
  for (int e = 0; e < NE; e++) {
    int start = spo[e] + scnt[e];
    int end = spo[e] + (((scnt[e] + 127) >> 7) << 7);
    for (int i = start + tid; i < end; i += 64) tos[i] = -1;
  }
}

// ---- scatter tokens into per-expert slots (block-aggregated atomics) ----
__global__ __launch_bounds__(256) void scatter_kernel(
    const int* __restrict__ tki, const int* __restrict__ poff,
    int* __restrict__ cursor, int* __restrict__ token_of_slot,
    int* __restrict__ slot_of_token) {
  __shared__ int lcnt[NE], lbase[NE];
  if (threadIdx.x < NE) lcnt[threadIdx.x] = 0;
  __syncthreads();
  int t = blockIdx.x * 256 + threadIdx.x;
  int e0 = tki[t * 2], e1 = tki[t * 2 + 1];
  int r0 = atomicAdd(&lcnt[e0], 1);
  int r1 = atomicAdd(&lcnt[e1], 1);
  __syncthreads();
  if (threadIdx.x < NE)
    lbase[threadIdx.x] = atomicAdd(&cursor[threadIdx.x], lcnt[threadIdx.x]);
  __syncthreads();
  int s0 = poff[e0] + lbase[e0] + r0;
  int s1 = poff[e1] + lbase[e1] + r1;
  token_of_slot[s0] = t;
  token_of_slot[s1] = t;
  slot_of_token[t * 2] = s0;
  slot_of_token[t * 2 + 1] = s1;
}

// ---- grouped GEMM: C[128x128]/block, 4 waves (2Mx2N), 16x16x32 bf16 MFMA ----
// (UNCHANGED from round 3 — verified winner: 2 blocks/CU, ~199us, 734 TF)
// Pipeline per 64-K tile:
//   P0: 12 ds_read_b128 -> bar -> 16 MFMA -> bar
//   P1:  4 ds_read_b128 -> bar -> 16 MFMA -> lgkmcnt(0) -> bar
//   ST:  8 global_load_lds (tile t+2, same-parity buffer); vmcnt(8) waits
//        tile t+1's 8 loads; bar.  Depth-2 prefetch, counted vmcnt.
// T2 swizzle: LDS linear; global SOURCE column inverse-permuted by (row&7);
// fragment ds_read applies the same XOR.
// MODE 1: A rows gathered via token_of_slot, relu(acc+b1) -> h
// MODE 2: A rows = slots (h),               (acc+b2)      -> y
template <int MODE>
__global__ __launch_bounds__(256, 2) void moe_gemm(
    const u16* __restrict__ A, const u16* __restrict__ Bt,
    const float* __restrict__ bias, u16* __restrict__ Hout,
    const int* __restrict__ tile_e, const int* __restrict__ tile_s0,
    const int* __restrict__ ntiles, const int* __restrict__ token_of_slot,
    int K, int N, int NB) {
  __shared__ u16 SM[32768];   // 64 KB: A0@0, A1@8192, B0@16384, B1@24576 (u16 units)

  const int nblk = blockIdx.x % NB;     // n fastest -> XCD-stationary B stripes
  const int tileid = blockIdx.x / NB;
  if (tileid >= ntiles[0]) return;
  const int e = tile_e[tileid];
  const int slot0 = tile_s0[tileid];
  const int n0 = nblk * 128;
  const int T = K >> 6;                 // 64-K tiles

  const int tid = threadIdx.x;
  const int lane = tid & 63;
  const int wave = tid >> 6;            // 0..3
  const int wm = wave >> 1;             // 0..1 : 64-row M half
  const int wn = wave & 1;              // 0..1 : 64-col N half

  // ---- staging source pointers (inverse-swizzled global columns) ----
  const int srow = tid >> 3;
  const int sslot = tid & 7;
  const u16* aB[4];
  const u16* bB[4];
  #pragma unroll
  for (int s = 0; s < 4; s++) {
    int row = s * 32 + srow;
    int scol = (sslot ^ (row & 7)) * 8;
    int arow;
    if (MODE == 1) { int t0 = token_of_slot[slot0 + row]; arow = t0 < 0 ? 0 : t0; }
    else arow = slot0 + row;
    aB[s] = A + (size_t)arow * K + scol;
  }
  const u16* bE = Bt + (size_t)e * N * K;
  #pragma unroll
  for (int s = 0; s < 4; s++) {
    int row = s * 32 + srow;
    int scol = (sslot ^ (row & 7)) * 8;
    bB[s] = bE + (size_t)(n0 + row) * K + scol;
  }

  // bias preload BEFORE stages + vmcnt(0) pin, so in-loop vmcnt counts are exact
  const int colq = lane & 15;
  float bv[4];
  #pragma unroll
  for (int n = 0; n < 4; n++) bv[n] = bias[(size_t)e * N + n0 + wn * 64 + n * 16 + colq];
  asm volatile("s_waitcnt vmcnt(0)" ::: "memory");

  const int wo = wave * 512;            // u16: wave's 1 KB slice within a site
  // ---- prologue: stage K-tiles 0 and 1 (8 loads each, in order) ----
  #pragma unroll
  for (int tt = 0; tt < 2; tt++) {
    const int kq = tt * 64;
    u16* LA = SM + tt * 8192;
    u16* LB = SM + 16384 + tt * 8192;
    #pragma unroll
    for (int s = 0; s < 4; s++) gl_lds16(aB[s] + kq, LA + s * 2048 + wo);
    #pragma unroll
    for (int s = 0; s < 4; s++) gl_lds16(bB[s] + kq, LB + s * 2048 + wo);
  }
  asm volatile("s_waitcnt vmcnt(8)" ::: "memory");   // tile0 landed
  __builtin_amdgcn_s_barrier();

  // ---- fragment ds_read addressing ----
  const int q4 = lane >> 4;
  const int sx = lane & 7;              // == frag_row & 7 (bases are mult of 16)
  const int sk0 = (q4 ^ sx) * 8;        // kstep0 slot (u16 off)
  const int sk1 = sk0 ^ 32;             // kstep1 slot: (s^4)*8
  const int aOff = (wm * 64 + (lane & 15)) * 64;
  const int bOff = (wn * 64 + (lane & 15)) * 64;

  f32x4 acc[4][4];
  #pragma unroll
  for (int i = 0; i < 4; i++)
    #pragma unroll
    for (int j = 0; j < 4; j++) acc[i][j] = (f32x4){0.f, 0.f, 0.f, 0.f};

  int kk = 128;                          // stages during tile t are for tile t+2
  for (int t = 0; t < T; ++t) {
    const int cb = t & 1;
    const u16* LA = SM + cb * 8192;
    const u16* LB = SM + 16384 + cb * 8192;
    u16* sLA = SM + cb * 8192;           // tile t+2 -> same-parity buffer
    u16* sLB = SM + 16384 + cb * 8192;
    s8bf af[4][2], bf[4][2];

    // ---- P0: 12 reads (A m0-3 both ks, B n0-1 both ks) -> bar -> 16 MFMA ----
    #pragma unroll
    for (int m = 0; m < 4; m++) {
      af[m][0] = *(const s8bf*)&LA[aOff + m * 1024 + sk0];
      af[m][1] = *(const s8bf*)&LA[aOff + m * 1024 + sk1];
    }
    #pragma unroll
    for (int n = 0; n < 2; n++) {
      bf[n][0] = *(const s8bf*)&LB[bOff + n * 1024 + sk0];
      bf[n][1] = *(const s8bf*)&LB[bOff + n * 1024 + sk1];
    }
    __builtin_amdgcn_sched_barrier(0);
    __builtin_amdgcn_s_barrier();
    __builtin_amdgcn_s_setprio(1);
    #pragma unroll
    for (int ks = 0; ks < 2; ks++)
      #pragma unroll
      for (int m = 0; m < 4; m++)
        #pragma unroll
        for (int n = 0; n < 2; n++)
          acc[m][n] = __builtin_amdgcn_mfma_f32_16x16x32_bf16(af[m][ks], bf[n][ks],
                                                              acc[m][n], 0, 0, 0);
    __builtin_amdgcn_s_setprio(0);
    __builtin_amdgcn_s_barrier();

    // ---- P1: 4 reads (B n2-3 both ks) -> bar -> 16 MFMA -> lgkm(0) -> bar ----
    #pragma unroll
    for (int n = 2; n < 4; n++) {
      bf[n][0] = *(const s8bf*)&LB[bOff + n * 1024 + sk0];
      bf[n][1] = *(const s8bf*)&LB[bOff + n * 1024 + sk1];
    }
    __builtin_amdgcn_sched_barrier(0);
    __builtin_amdgcn_s_barrier();
    __builtin_amdgcn_s_setprio(1);
    #pragma unroll
    for (int ks = 0; ks < 2; ks++)
      #pragma unroll
      for (int m = 0; m < 4; m++)
        #pragma unroll
        for (int n = 2; n < 4; n++)
          acc[m][n] = __builtin_amdgcn_mfma_f32_16x16x32_bf16(af[m][ks], bf[n][ks],
                                                              acc[m][n], 0, 0, 0);
    __builtin_amdgcn_s_setprio(0);
    asm volatile("s_waitcnt lgkmcnt(0)" ::: "memory");  // all buf-cb reads done
    __builtin_amdgcn_sched_barrier(0);
    __builtin_amdgcn_s_barrier();                       // ...across all waves

    // ---- ST: stage tile t+2 into buf cb; wait tile t+1's loads; bar ----
    if (t + 2 < T) {
      #pragma unroll
      for (int s = 0; s < 4; s++) gl_lds16(aB[s] + kk, sLA + s * 2048 + wo);
      #pragma unroll
      for (int s = 0; s < 4; s++) gl_lds16(bB[s] + kk, sLB + s * 2048 + wo);
    }
    __builtin_amdgcn_sched_barrier(0);
    if (t < T - 2)       asm volatile("s_waitcnt vmcnt(8)" ::: "memory");
    else if (t == T - 2) asm volatile("s_waitcnt vmcnt(0)" ::: "memory");
    if (t < T - 1) {
      __builtin_amdgcn_sched_barrier(0);
      __builtin_amdgcn_s_barrier();
    }
    kk += 64;
  }

  // ---- epilogue: stage 128x128 bf16 in LDS, stream out coalesced b128 rows ----
  __syncthreads();
  const int rq = (lane >> 4) * 4;
  #pragma unroll
  for (int nt = 0; nt < 4; nt++) {
    int lcol = wn * 64 + nt * 16 + colq;
    #pragma unroll
    for (int mt = 0; mt < 4; mt++) {
      int rowbase = wm * 64 + mt * 16 + rq;
      #pragma unroll
      for (int r = 0; r < 4; r++) {
        float v = acc[mt][nt][r] + bv[nt];
        if (MODE == 1) v = fmaxf(v, 0.f);
        SM[(rowbase + r) * LSTR + lcol] = f2b(v);
      }
    }
  }
  __syncthreads();
  #pragma unroll
  for (int k = 0; k < 8; k++) {
    int ch = k * 256 + tid;
    int row = ch >> 4;
    int cp = (ch & 15) * 8;
    uint4 v = *(const uint4*)&SM[row * LSTR + cp];
    *(uint4*)&Hout[(size_t)(slot0 + row) * N + n0 + cp] = v;
  }
}

// ---- combine: out[t] = w0*y[s0] + w1*y[s1] (y bf16, out fp32) ----
__global__ __launch_bounds__(256) void combine_kernel(
    const u16* __restrict__ y, const int* __restrict__ sot,
    const float* __restrict__ tkw, float* __restrict__ out) {
  int wave = threadIdx.x >> 6, lane = threadIdx.x & 63;
  int t = blockIdx.x * 4 + wave;
  int s0 = sot[t * 2], s1 = sot[t * 2 + 1];
  float w0 = tkw[t * 2], w1 = tkw[t * 2 + 1];
  const u16* y0 = y + (size_t)s0 * DIM;
  const u16* y1 = y + (size_t)s1 * DIM;
  float* op = out + (size_t)t * DIM;
  #pragma unroll
  for (int i = 0; i < 4; i++) {
    int d = i * 256 + lane * 4;
    uint2 a = *(const uint2*)(y0 + d);
    uint2 b = *(const uint2*)(y1 + d);
    float4 o;
    o.x = w0 * b2f((u16)(a.x & 0xFFFF)) + w1 * b2f((u16)(b.x & 0xFFFF));
    o.y = w0 * b2f((u16)(a.x >> 16))    + w1 * b2f((u16)(b.x >> 16));
    o.z = w0 * b2f((u16)(a.y & 0xFFFF)) + w1 * b2f((u16)(b.y & 0xFFFF));
    o.w = w0 * b2f((u16)(a.y >> 16))    + w1 * b2f((u16)(b.y >> 16));
    *(float4*)(op + d) = o;
  }
}

extern "C" void kernel_launch(void* const* d_in, const int* in_sizes, int n_in,
                              void* d_out, int out_size, void* d_ws, size_t ws_size,
                              hipStream_t stream) {
  const float* x  = (const float*)d_in[0];
  const float* Wr = (const float*)d_in[1];
  const float* br = (const float*)d_in[2];
  const float* W1 = (const float*)d_in[3];
  const float* b1 = (const float*)d_in[4];
  const float* W2 = (const float*)d_in[5];
  const float* b2 = (const float*)d_in[6];
  float* out = (float*)d_out;
  char* ws = (char*)d_ws;

  u16*   W1t  = (u16*)(ws + OFF_W1T);
  u16*   W2t  = (u16*)(ws + OFF_W2T);
  u16*   ybuf = (u16*)(ws + OFF_Y);     // overlays W1t (dead after GEMM1)
  u16*   xb   = (u16*)(ws + OFF_XB);
  u16*   hbuf = (u16*)(ws + OFF_H);
  int*   tos  = (int*)(ws + OFF_TOS);
  int*   sot  = (int*)(ws + OFF_SOT);
  int*   tki  = (int*)(ws + OFF_TKI);
  float* tkw  = (float*)(ws + OFF_TKW);
  int*   cnt  = (int*)(ws + OFF_CNT);
  int*   pof  = (int*)(ws + OFF_POF);
  int*   cur  = (int*)(ws + OFF_CUR);
  int*   nt   = (int*)(ws + OFF_NT);
  int*   te   = (int*)(ws + OFF_TE);
  int*   ts   = (int*)(ws + OFF_TS);

  hipMemsetAsync(cnt, 0, 8 * sizeof(int), stream);

  // tiles: NE * (R/256) * (C/64)
  transpose_to_bf16<<<dim3(NE * (DIM / 256) * (HID / 64)), 256, 0, stream>>>(W1, W1t, DIM, HID);
  transpose_to_bf16<<<dim3(NE * (HID / 256) * (DIM / 64)), 256, 0, stream>>>(W2, W2t, HID, DIM);
  router_kernel<<<dim3(N_TOK / 4), 256, 0, stream>>>(x, Wr, br, xb, tki, tkw, cnt);
  plan_kernel<<<dim3(1), 64, 0, stream>>>(cnt, pof, cur, nt, te, ts, tos);
  scatter_kernel<<<dim3(N_TOK / 256), 256, 0, stream>>>(tki, pof, cur, tos, sot);

  // 128x128 tiles; n-block fastest -> XCD-stationary B stripes; 2 blocks/CU
  moe_gemm<1><<<dim3((MAX_SLOTS / 128) * (HID / 128)), 256, 0, stream>>>(
      xb, W1t, b1, hbuf, te, ts, nt, tos, DIM, HID, HID / 128);
  moe_gemm<2><<<dim3((MAX_SLOTS / 128) * (DIM / 128)), 256, 0, stream>>>(
      hbuf, W2t, b2, ybuf, te, ts, nt, tos, HID, DIM, DIM / 128);
  combine_kernel<<<dim3(N_TOK / 4), 256, 0, stream>>>(ybuf, sot, tkw, out);
}